// Round 6
// baseline (230.137 us; speedup 1.0000x reference)
//
#include <hip/hip_runtime.h>
#include <hip/hip_bf16.h>

#define NQ   50000
#define NKV  50000
#define CC   128
#define GG   8
#define SS   16
#define CSH  16

typedef short    bf16x8 __attribute__((ext_vector_type(8)));
typedef float    f32x4  __attribute__((ext_vector_type(4)));
typedef unsigned u32x4  __attribute__((ext_vector_type(4)));
typedef unsigned u32x2  __attribute__((ext_vector_type(2)));
typedef int      i32x4  __attribute__((ext_vector_type(4)));

__device__ __forceinline__ float bf_lo(unsigned u){ union{unsigned x; float f;} v; v.x = u << 16;        return v.f; }
__device__ __forceinline__ float bf_hi(unsigned u){ union{unsigned x; float f;} v; v.x = u & 0xffff0000u; return v.f; }
__device__ __forceinline__ unsigned short f2bfu(float f){
    __hip_bfloat16 h = __float2bfloat16(f);
    return *reinterpret_cast<unsigned short*>(&h);
}
__device__ __forceinline__ short f2bfs(float f){
    __hip_bfloat16 h = __float2bfloat16(f);
    return *reinterpret_cast<short*>(&h);
}

// Load 16 contiguous bf16 (32B, >=16B aligned) -> 16 fp32 (cached path: K/V)
__device__ __forceinline__ void load16bf(const __hip_bfloat16* ptr, float* o){
    const u32x4* p4 = reinterpret_cast<const u32x4*>(ptr);
    u32x4 a = p4[0]; u32x4 b = p4[1];
    o[0]=bf_lo(a[0]);  o[1]=bf_hi(a[0]);  o[2]=bf_lo(a[1]);  o[3]=bf_hi(a[1]);
    o[4]=bf_lo(a[2]);  o[5]=bf_hi(a[2]);  o[6]=bf_lo(a[3]);  o[7]=bf_hi(a[3]);
    o[8]=bf_lo(b[0]);  o[9]=bf_hi(b[0]);  o[10]=bf_lo(b[1]); o[11]=bf_hi(b[1]);
    o[12]=bf_lo(b[2]); o[13]=bf_hi(b[2]); o[14]=bf_lo(b[3]); o[15]=bf_hi(b[3]);
}

// Non-temporal variant (single-use streams: Q)
__device__ __forceinline__ void load16bf_nt(const __hip_bfloat16* ptr, float* o){
    const u32x4* p4 = reinterpret_cast<const u32x4*>(ptr);
    u32x4 a = __builtin_nontemporal_load(p4);
    u32x4 b = __builtin_nontemporal_load(p4 + 1);
    o[0]=bf_lo(a[0]);  o[1]=bf_hi(a[0]);  o[2]=bf_lo(a[1]);  o[3]=bf_hi(a[1]);
    o[4]=bf_lo(a[2]);  o[5]=bf_hi(a[2]);  o[6]=bf_lo(a[3]);  o[7]=bf_hi(a[3]);
    o[8]=bf_lo(b[0]);  o[9]=bf_hi(b[0]);  o[10]=bf_lo(b[1]); o[11]=bf_hi(b[1]);
    o[12]=bf_lo(b[2]); o[13]=bf_hi(b[2]); o[14]=bf_lo(b[3]); o[15]=bf_hi(b[3]);
}

// Load 8 contiguous f32 (32B), convert to bf16x8 fragment
__device__ __forceinline__ bf16x8 cvt8(const float* p){
    const f32x4* q = reinterpret_cast<const f32x4*>(p);
    f32x4 u = q[0], v = q[1];
    bf16x8 r;
    r[0]=f2bfs(u[0]); r[1]=f2bfs(u[1]); r[2]=f2bfs(u[2]); r[3]=f2bfs(u[3]);
    r[4]=f2bfs(v[0]); r[5]=f2bfs(v[1]); r[6]=f2bfs(v[2]); r[7]=f2bfs(v[3]);
    return r;
}

// ---------------------------------------------------------------------------
// Kernel 1: Q/K/V projections.  out[n][c] = sum_k src[n][k] * W[c][k] + b[c]
// Block = 256 threads = 4 waves, 128 rows/block (32 rows/wave).
// W (f32) staged once per block into LDS in MFMA A-fragment order.
// R5: staging global reads are lane-contiguous (o = i*2048 + tid*8 -> 32B
// lane stride, full cache-line use) instead of 256-B-strided.
// Outputs: Q -> Qf (row stride 128); K/V -> KVf interleaved rows of 256
// elems ([K 0..127 | V 128..255]), written non-temporally (single-use
// stream; keep L2 for x/x2/W).
// ---------------------------------------------------------------------------
__global__ __launch_bounds__(256) void qkv_gemm(
    const float* __restrict__ x,
    const float* __restrict__ x2,
    const float* __restrict__ Wq, const float* __restrict__ Wk,
    const float* __restrict__ Wv,
    const float* __restrict__ bq, const float* __restrict__ bk,
    const float* __restrict__ bv,
    __hip_bfloat16* __restrict__ Qf,     // (NQ, 128)
    __hip_bfloat16* __restrict__ KVf)    // (NKV, 256) interleaved K|V
{
    __shared__ short lds16[16384];   // 32 KB: 8 tiles x 4 kb x 64 lanes x 8 halfwords

    const int which = blockIdx.y;
    const float* src;  const float* W;  const float* bias;
    short* dstb; int dstride, hoff;
    if (which == 0)      { src = x;  W = Wq; bias = bq; dstb = (short*)Qf;  dstride = CC;     hoff = 0;  }
    else if (which == 1) { src = x2; W = Wk; bias = bk; dstb = (short*)KVf; dstride = 2 * CC; hoff = 0;  }
    else                 { src = x2; W = Wv; bias = bv; dstb = (short*)KVf; dstride = 2 * CC; hoff = CC; }
    const int nrows = NQ;            // == NKV

    // --- stage W into LDS (f32 -> bf16), fragment order, coalesced reads ---
    const int tid = threadIdx.x;
    #pragma unroll
    for (int i = 0; i < 8; ++i) {
        const int o   = i * 2048 + tid * 8;        // linear f32 offset in W
        const bf16x8 v = cvt8(W + o);
        const int row = o >> 7, col = o & 127;
        const int lchunk = (((row >> 4) * 4 + (col >> 5)) << 6)
                         + (((col >> 3) & 3) << 4) + (row & 15);
        *reinterpret_cast<bf16x8*>(&lds16[lchunk * 8]) = v;
    }

    const int wave = tid >> 6;
    const int lane = tid & 63;
    const int r  = lane & 15;
    const int kq = lane >> 4;
    const int base = blockIdx.x * 128 + wave * 32;

    // --- B-fragments: this wave's 32 x-rows (2 m-tiles x 4 k-blocks) ---
    bf16x8 bfrag[2][4];
    #pragma unroll
    for (int mt = 0; mt < 2; ++mt) {
        int row = base + mt * 16 + r;
        if (row >= nrows) row = nrows - 1;         // clamp; stores guarded
        const float* xr = src + (size_t)row * CC + kq * 8;
        #pragma unroll
        for (int kb = 0; kb < 4; ++kb)
            bfrag[mt][kb] = cvt8(xr + kb * 32);
    }

    __syncthreads();

    // --- main loop over 8 column tiles ---
    #pragma unroll
    for (int t = 0; t < 8; ++t) {
        bf16x8 af[4];
        #pragma unroll
        for (int kb = 0; kb < 4; ++kb)
            af[kb] = *reinterpret_cast<const bf16x8*>(
                &lds16[(((t * 4 + kb) << 6) + lane) * 8]);

        f32x4 acc0 = {0.f,0.f,0.f,0.f}, acc1 = {0.f,0.f,0.f,0.f};
        #pragma unroll
        for (int kb = 0; kb < 4; ++kb) {
            acc0 = __builtin_amdgcn_mfma_f32_16x16x32_bf16(af[kb], bfrag[0][kb], acc0, 0, 0, 0);
            acc1 = __builtin_amdgcn_mfma_f32_16x16x32_bf16(af[kb], bfrag[1][kb], acc1, 0, 0, 0);
        }

        const f32x4 bi = *reinterpret_cast<const f32x4*>(bias + t * 16 + kq * 4);
        #pragma unroll
        for (int mt = 0; mt < 2; ++mt) {
            const int row = base + mt * 16 + r;
            if (row < nrows) {
                const f32x4 a = mt ? acc1 : acc0;
                u32x2 pk;
                pk[0] = (unsigned)f2bfu(a[0] + bi[0]) | ((unsigned)f2bfu(a[1] + bi[1]) << 16);
                pk[1] = (unsigned)f2bfu(a[2] + bi[2]) | ((unsigned)f2bfu(a[3] + bi[3]) << 16);
                __builtin_nontemporal_store(pk, reinterpret_cast<u32x2*>(
                    dstb + (size_t)row * dstride + hoff + t * 16 + kq * 4));
            }
        }
    }
}

// ---------------------------------------------------------------------------
// Kernel 2: fused gather + positional MLP + grouped attention, single pass,
// online (flash-style) softmax (round-3 lesson: PE term reaches ~250 —
// unshifted exp overflows). K/V interleaved rows: one base address per
// neighbor, 4 dwordx4 at immediate offsets 0/16/512/528 B.
// Q/idx loaded non-temporally, out stored non-temporally (single-use
// streams; preserve L2 for the KV gather working set).
// ---------------------------------------------------------------------------
__global__ __launch_bounds__(256) void attn_kernel(
    const float* __restrict__ p,        // (NQ,3)
    const float* __restrict__ p2,       // (NKV,3)
    const int*   __restrict__ idx,      // (NQ,SS)
    const float* __restrict__ W1,       // (3,3)
    const float* __restrict__ b1,       // (3,)
    const float* __restrict__ bn_gamma,
    const float* __restrict__ bn_beta,
    const float* __restrict__ bn_mean,
    const float* __restrict__ bn_var,
    const float* __restrict__ W2,       // (16,3)
    const float* __restrict__ b2,       // (16,)
    const __hip_bfloat16* __restrict__ Qf,   // (NQ,128) bf16
    const __hip_bfloat16* __restrict__ KVf,  // (NKV,256) bf16 interleaved
    float* __restrict__ out)            // (NQ,CC) f32
{
    const int tid = blockIdx.x * 256 + threadIdx.x;
    if (tid >= NQ * GG) return;
    const int n = tid >> 3;
    const int g = tid & 7;

    // --- fold BN into the 3x3 conv ---
    float fw1[3][3], fb1[3];
    #pragma unroll
    for (int j = 0; j < 3; ++j) {
        const float sc = bn_gamma[j] * rsqrtf(bn_var[j] + 1e-5f);
        #pragma unroll
        for (int k = 0; k < 3; ++k) fw1[j][k] = W1[j*3 + k] * sc;
        fb1[j] = (b1[j] - bn_mean[j]) * sc + bn_beta[j];
    }
    const float w2q0 = W2[g*3+0],     w2q1 = W2[g*3+1],     w2q2 = W2[g*3+2];
    const float w2k0 = W2[(g+8)*3+0], w2k1 = W2[(g+8)*3+1], w2k2 = W2[(g+8)*3+2];
    const float b2q = b2[g], b2k = b2[g+8];

    const float px = p[(size_t)n*3+0];
    const float py = p[(size_t)n*3+1];
    const float pz = p[(size_t)n*3+2];

    // --- neighbor indices (16 ints = 64B aligned, single-use stream) ---
    int nbr[SS];
    {
        const i32x4* ip = reinterpret_cast<const i32x4*>(idx + (size_t)n * SS);
        i32x4 i0 = __builtin_nontemporal_load(ip);
        i32x4 i1 = __builtin_nontemporal_load(ip + 1);
        i32x4 i2 = __builtin_nontemporal_load(ip + 2);
        i32x4 i3 = __builtin_nontemporal_load(ip + 3);
        nbr[0]=i0[0]; nbr[1]=i0[1]; nbr[2]=i0[2]; nbr[3]=i0[3];
        nbr[4]=i1[0]; nbr[5]=i1[1]; nbr[6]=i1[2]; nbr[7]=i1[3];
        nbr[8]=i2[0]; nbr[9]=i2[1]; nbr[10]=i2[2]; nbr[11]=i2[3];
        nbr[12]=i3[0]; nbr[13]=i3[1]; nbr[14]=i3[2]; nbr[15]=i3[3];
    }

    // --- query fragment for this group (single-use) ---
    float q[CSH];
    load16bf_nt(Qf + (size_t)n * CC + g * CSH, q);

    // --- single fused pass with online softmax ---
    float acc[CSH];
    #pragma unroll
    for (int c = 0; c < CSH; ++c) acc[c] = 0.f;
    float sum = 0.f;
    float m = -3.0e38f;

    #pragma unroll 4
    for (int s = 0; s < SS; ++s) {
        const int i = nbr[s];
        const __hip_bfloat16* kv = KVf + (size_t)i * (2 * CC) + g * CSH;

        float kk[CSH], vv[CSH];
        load16bf(kv, kk);            // K slice at +0
        load16bf(kv + CC, vv);       // V slice at +256 B immediate

        const float rx = p2[(size_t)i*3+0] - px;
        const float ry = p2[(size_t)i*3+1] - py;
        const float rz = p2[(size_t)i*3+2] - pz;
        const float h0 = fmaxf(fw1[0][0]*rx + fw1[0][1]*ry + fw1[0][2]*rz + fb1[0], 0.f);
        const float h1 = fmaxf(fw1[1][0]*rx + fw1[1][1]*ry + fw1[1][2]*rz + fb1[1], 0.f);
        const float h2 = fmaxf(fw1[2][0]*rx + fw1[2][1]*ry + fw1[2][2]*rz + fb1[2], 0.f);
        const float prq = w2q0*h0 + w2q1*h1 + w2q2*h2 + b2q;
        const float prk = w2k0*h0 + w2k1*h1 + w2k2*h2 + b2k;

        float d = 0.f;
        #pragma unroll
        for (int c = 0; c < CSH; ++c) d += (kk[c] + prk) * (q[c] + prq);
        d *= 0.25f;   // 1/sqrt(CS) = 0.25

        const float mnew = fmaxf(m, d);
        const float corr = __expf(m - mnew);   // 1.0 when max unchanged
        const float w    = __expf(d - mnew);
        sum = sum * corr + w;
        #pragma unroll
        for (int c = 0; c < CSH; ++c) acc[c] = acc[c] * corr + w * vv[c];
        m = mnew;
    }

    const float inv = 1.f / sum;

    // --- store 16 f32 non-temporally (out is never re-read) ---
    f32x4* op = reinterpret_cast<f32x4*>(out + (size_t)n * CC + g * CSH);
    f32x4 o0 = {acc[0]*inv,  acc[1]*inv,  acc[2]*inv,  acc[3]*inv};
    f32x4 o1 = {acc[4]*inv,  acc[5]*inv,  acc[6]*inv,  acc[7]*inv};
    f32x4 o2 = {acc[8]*inv,  acc[9]*inv,  acc[10]*inv, acc[11]*inv};
    f32x4 o3 = {acc[12]*inv, acc[13]*inv, acc[14]*inv, acc[15]*inv};
    __builtin_nontemporal_store(o0, op);
    __builtin_nontemporal_store(o1, op + 1);
    __builtin_nontemporal_store(o2, op + 2);
    __builtin_nontemporal_store(o3, op + 3);
}

// ---------------------------------------------------------------------------
extern "C" void kernel_launch(void* const* d_in, const int* in_sizes, int n_in,
                              void* d_out, int out_size, void* d_ws, size_t ws_size,
                              hipStream_t stream) {
    const float* p   = (const float*)d_in[0];
    const float* x   = (const float*)d_in[1];
    const float* p2  = (const float*)d_in[2];
    const float* x2  = (const float*)d_in[3];
    const int*   idx = (const int*)d_in[4];
    const float* Wq  = (const float*)d_in[5];
    const float* bq  = (const float*)d_in[6];
    const float* Wk  = (const float*)d_in[7];
    const float* bk  = (const float*)d_in[8];
    const float* Wv  = (const float*)d_in[9];
    const float* bv  = (const float*)d_in[10];
    const float* W1  = (const float*)d_in[11];
    const float* b1  = (const float*)d_in[12];
    const float* bng = (const float*)d_in[13];
    const float* bnb = (const float*)d_in[14];
    const float* bnm = (const float*)d_in[15];
    const float* bnv = (const float*)d_in[16];
    const float* W2  = (const float*)d_in[17];
    const float* b2  = (const float*)d_in[18];
    float* out = (float*)d_out;

    // workspace: Qf (12.8 MB) | KVf interleaved (25.6 MB)
    __hip_bfloat16* Qf  = (__hip_bfloat16*)d_ws;
    __hip_bfloat16* KVf = Qf + (size_t)NQ * CC;

    // 50000 rows / 128 rows-per-block = 390.6 -> 391 blocks; y: Q,K,V
    qkv_gemm<<<dim3(391, 3), 256, 0, stream>>>(
        x, x2, Wq, Wk, Wv, bq, bk, bv, Qf, KVf);

    const int nthreads = NQ * GG;
    attn_kernel<<<(nthreads + 255) / 256, 256, 0, stream>>>(
        p, p2, idx, W1, b1, bng, bnb, bnm, bnv, W2, b2, Qf, KVf, out);
}